// Round 10
// baseline (313.721 us; speedup 1.0000x reference)
//
#include <hip/hip_runtime.h>
#include <math.h>

#define XROWS 12544      // 256*49
#define YROWS 2048       // 64*32
#define HD 512
#define NM 49
#define NL 32
#define MP1 50
#define LP1 33
#define BSTRIDE 1650     // (m+1)*(L+1)
#define INVREG 10.0f

typedef __attribute__((ext_vector_type(8))) short short8;
typedef __attribute__((ext_vector_type(4))) float floatx4;

__device__ __forceinline__ unsigned short f2bf(float f) {
    unsigned int u = __builtin_bit_cast(unsigned int, f);
    u = (u + 0x7FFFu + ((u >> 16) & 1u)) >> 16;
    return (unsigned short)u;
}

// ------------------------------------------------ normalize + cast to bf16
__global__ __launch_bounds__(256) void normcvt_kernel(
    const float* __restrict__ x, const float* __restrict__ y,
    unsigned short* __restrict__ xb, unsigned short* __restrict__ yb)
{
    const int wid = blockIdx.x * 4 + (threadIdx.x >> 6);
    const int lane = threadIdx.x & 63;
    if (wid >= XROWS + YROWS) return;
    const float* src;
    unsigned short* dst;
    if (wid < XROWS) { src = x + (size_t)wid * HD;           dst = xb + (size_t)wid * HD; }
    else             { src = y + (size_t)(wid - XROWS) * HD; dst = yb + (size_t)(wid - XROWS) * HD; }
    const float4 v0 = *(const float4*)(src + lane * 8);
    const float4 v1 = *(const float4*)(src + lane * 8 + 4);
    float s = v0.x*v0.x + v0.y*v0.y + v0.z*v0.z + v0.w*v0.w
            + v1.x*v1.x + v1.y*v1.y + v1.z*v1.z + v1.w*v1.w;
    #pragma unroll
    for (int o = 32; o > 0; o >>= 1) s += __shfl_xor(s, o, 64);
    const float inv = 1.0f / fmaxf(sqrtf(s), 1e-12f);
    short8 ov;
    ov[0] = (short)f2bf(v0.x * inv); ov[1] = (short)f2bf(v0.y * inv);
    ov[2] = (short)f2bf(v0.z * inv); ov[3] = (short)f2bf(v0.w * inv);
    ov[4] = (short)f2bf(v1.x * inv); ov[5] = (short)f2bf(v1.y * inv);
    ov[6] = (short)f2bf(v1.z * inv); ov[7] = (short)f2bf(v1.w * inv);
    *(short8*)(dst + lane * 8) = ov;
}

// ------------------------------------------------ fused scores(MFMA) + sinkhorn
// One wave per pair. Phase 1: 49x32 scores via MFMA from L2-resident bf16.
// Phase 2: repack acc -> row-major LDS [50][36]. Phase 3: kr[33] regs (exp),
// col-major overlay (STRIDE 52 >= 50 rows! r9 bug was stride 36) -> kc[52].
// Iterations: eu/ev broadcast via wave-uniform LDS float4 reads, state in regs.
__global__ __launch_bounds__(256, 4) void fused_kernel(
    const unsigned short* __restrict__ xb, const unsigned short* __restrict__ yb,
    const int* __restrict__ ymask,
    const float* __restrict__ d_im, const float* __restrict__ d_lang,
    float* __restrict__ outZ, float* __restrict__ scores2)
{
    const int w    = threadIdx.x >> 6;
    const int lane = threadIdx.x & 63;
    const int pair = blockIdx.x * 4 + w;
    const int i = pair >> 6, j = pair & 63;
    __shared__ alignas(16) float SAll[4][1888];   // 29.5 KB/block
    float* RT = SAll[w];                   // 1800: rowtile -> colmajor(52) -> Zm staging
    float* EV = RT + 1800;                 // 36 (pad [33..35]=0)
    float* EU = RT + 1836;                 // 52 (pad [50..51]=0)
    float* base = outZ + (size_t)pair * BSTRIDE;

    // ---- masks / dustbins ----
    const int mval = (lane < NL) ? (ymask[j * NL + lane] != 0) : 1;
    const unsigned long long vbm = __ballot(lane < NL && !mval);  // bit c = col valid
    const float ns = (float)__popcll(vbm);
    const float kim   = __expf(fminf(fmaxf(d_im[0],   -1.f), 1.f) * INVREG);
    const float klang = __expf(fminf(fmaxf(d_lang[0], -1.f), 1.f) * INVREG);

    // ---- phase 1: scores via MFMA ----
    const int la = lane & 15;
    const int koff = (lane >> 4) * 8;
    const unsigned short* xr0 = xb + ((size_t)i * NM + la) * HD + koff;
    const unsigned short* xr1 = xr0 + 16 * HD;
    const unsigned short* xr2 = xr0 + 32 * HD;
    const unsigned short* xr3 = xb + ((size_t)i * NM + 48) * HD + koff;  // rows 49..63 dup of 48 (unused)
    const unsigned short* yr0 = yb + ((size_t)j * NL + la) * HD + koff;
    const unsigned short* yr1 = yr0 + 16 * HD;

    floatx4 acc[4][2] = {};
    #pragma unroll
    for (int kt = 0; kt < 16; ++kt) {
        const int k0 = kt * 32;
        const short8 a0 = *(const short8*)(xr0 + k0);
        const short8 a1 = *(const short8*)(xr1 + k0);
        const short8 a2 = *(const short8*)(xr2 + k0);
        const short8 a3 = *(const short8*)(xr3 + k0);
        const short8 b0 = *(const short8*)(yr0 + k0);
        const short8 b1 = *(const short8*)(yr1 + k0);
        acc[0][0] = __builtin_amdgcn_mfma_f32_16x16x32_bf16(a0, b0, acc[0][0], 0, 0, 0);
        acc[0][1] = __builtin_amdgcn_mfma_f32_16x16x32_bf16(a0, b1, acc[0][1], 0, 0, 0);
        acc[1][0] = __builtin_amdgcn_mfma_f32_16x16x32_bf16(a1, b0, acc[1][0], 0, 0, 0);
        acc[1][1] = __builtin_amdgcn_mfma_f32_16x16x32_bf16(a1, b1, acc[1][1], 0, 0, 0);
        acc[2][0] = __builtin_amdgcn_mfma_f32_16x16x32_bf16(a2, b0, acc[2][0], 0, 0, 0);
        acc[2][1] = __builtin_amdgcn_mfma_f32_16x16x32_bf16(a2, b1, acc[2][1], 0, 0, 0);
        acc[3][0] = __builtin_amdgcn_mfma_f32_16x16x32_bf16(a3, b0, acc[3][0], 0, 0, 0);
        acc[3][1] = __builtin_amdgcn_mfma_f32_16x16x32_bf16(a3, b1, acc[3][1], 0, 0, 0);
    }

    // ---- phase 2: repack acc -> RT row-major stride 36 (16B-aligned rows) ----
    #pragma unroll
    for (int mi = 0; mi < 4; ++mi) {
        #pragma unroll
        for (int q = 0; q < 4; ++q) {
            const int row = mi * 16 + (lane >> 4) * 4 + q;
            if (row < MP1) {
                RT[row * 36 + la]      = acc[mi][0][q];
                RT[row * 36 + 16 + la] = acc[mi][1][q];
            }
        }
    }
    asm volatile("s_waitcnt lgkmcnt(0)" ::: "memory");
    __builtin_amdgcn_sched_barrier(0);

    // ---- phase 3a: row p -> kr[33] (exp applied) ----
    float kr[33];
    #pragma unroll
    for (int c = 0; c < 33; ++c) kr[c] = 0.f;
    if (lane < NM) {
        #pragma unroll
        for (int q2 = 0; q2 < 8; ++q2) {
            const float4 v = *(const float4*)&RT[lane * 36 + q2 * 4];
            kr[q2*4+0] = ((vbm >> (q2*4+0)) & 1ull) ? __expf(v.x * INVREG) : 0.f;
            kr[q2*4+1] = ((vbm >> (q2*4+1)) & 1ull) ? __expf(v.y * INVREG) : 0.f;
            kr[q2*4+2] = ((vbm >> (q2*4+2)) & 1ull) ? __expf(v.z * INVREG) : 0.f;
            kr[q2*4+3] = ((vbm >> (q2*4+3)) & 1ull) ? __expf(v.w * INVREG) : 0.f;
        }
    } else if (lane == NM) {               // dustbin row p=49
        #pragma unroll
        for (int c = 0; c < NL; ++c) kr[c] = ((vbm >> c) & 1ull) ? klang : 0.f;
    }
    kr[32] = kim;
    asm volatile("s_waitcnt lgkmcnt(0)" ::: "memory");
    __builtin_amdgcn_sched_barrier(0);

    // ---- phase 3b: col-major overlay (stride 52) + EV/EU init ----
    if (lane < MP1) {
        #pragma unroll
        for (int c = 0; c < 33; ++c) RT[c * 52 + lane] = kr[c];
    } else if (lane < 52) {                // zero pad rows 50,51 of every column
        #pragma unroll
        for (int c = 0; c < 33; ++c) RT[c * 52 + lane] = 0.f;
    }
    const bool colA = (lane < NL) ? (((vbm >> lane) & 1ull) != 0ull) : (lane == NL);
    if (lane < LP1)                 EV[lane] = colA ? 1.f : 0.f;
    else if (lane < 36)             EV[lane] = 0.f;               // pads
    if (lane >= 36 && lane < 38)    EU[lane + 14] = 0.f;          // EU[50],EU[51]
    asm volatile("s_waitcnt lgkmcnt(0)" ::: "memory");
    __builtin_amdgcn_sched_barrier(0);

    // ---- phase 3c: col l -> kc[52] regs (exact: pads are true zeros) ----
    float kc[52];
    #pragma unroll
    for (int p = 0; p < 52; ++p) kc[p] = 0.f;
    if (lane < LP1) {
        #pragma unroll
        for (int q = 0; q < 13; ++q) {
            const float4 v = *(const float4*)&RT[lane * 52 + q * 4];
            kc[q*4+0] = v.x; kc[q*4+1] = v.y; kc[q*4+2] = v.z; kc[q*4+3] = v.w;
        }
    }

    const float mup = (lane < NM) ? 1.f : ns;     // lane 49 -> ns
    const float nup = (lane < NL) ? 1.f : 49.f;   // lane 32 -> m
    float eu = 0.f;

    // ---- 10 iterations: broadcasts via wave-uniform LDS float4 reads ----
    for (int it = 0; it < 10; ++it) {
        // u-phase: S_p = sum_c kr[c]*ev[c]
        float a0 = 0.f, a1 = 0.f, a2 = 0.f, a3 = 0.f;
        #pragma unroll
        for (int q = 0; q < 8; ++q) {
            const float4 e = *(const float4*)&EV[q * 4];   // broadcast read
            a0 = fmaf(kr[q*4+0], e.x, a0);
            a1 = fmaf(kr[q*4+1], e.y, a1);
            a2 = fmaf(kr[q*4+2], e.z, a2);
            a3 = fmaf(kr[q*4+3], e.w, a3);
        }
        const float e32 = EV[32];
        eu = __fdividef(mup, ((a0 + a1) + (a2 + a3)) + kr[32] * e32);
        if (lane < MP1) EU[lane] = eu;
        asm volatile("s_waitcnt lgkmcnt(0)" ::: "memory");
        __builtin_amdgcn_sched_barrier(0);

        // v-phase: S_l = sum_p kc[p]*eu[p]
        if (lane < LP1) {
            float b0 = 0.f, b1 = 0.f, b2 = 0.f, b3 = 0.f;
            #pragma unroll
            for (int q = 0; q < 13; ++q) {
                const float4 u4 = *(const float4*)&EU[q * 4];  // broadcast read
                b0 = fmaf(kc[q*4+0], u4.x, b0);
                b1 = fmaf(kc[q*4+1], u4.y, b1);
                b2 = fmaf(kc[q*4+2], u4.z, b2);
                b3 = fmaf(kc[q*4+3], u4.w, b3);
            }
            const float Sv = (b0 + b1) + (b2 + b3);
            EV[lane] = colA ? __fdividef(nup, Sv) : 0.f;
        }
        asm volatile("s_waitcnt lgkmcnt(0)" ::: "memory");
        __builtin_amdgcn_sched_barrier(0);
    }

    // ---- epilogue: Zm = kr*eu*ev; ot = sum (10*score)*zm  (ln kr = 10*score) ----
    float ot = 0.f;
    if (lane < MP1) {
        #pragma unroll
        for (int q = 0; q < 8; ++q) {
            const float4 e = *(const float4*)&EV[q * 4];
            #pragma unroll
            for (int t = 0; t < 4; ++t) {
                const int c = q * 4 + t;
                const float evc = (t == 0) ? e.x : (t == 1) ? e.y : (t == 2) ? e.z : e.w;
                const float zm = kr[c] * eu * evc;
                RT[lane * 33 + c] = zm;                      // stage over dead colmajor
                if (lane < NM && kr[c] > 0.f)
                    ot = fmaf(__logf(kr[c]), zm, ot);
            }
        }
        const float zm32 = kr[32] * eu * EV[32];
        RT[lane * 33 + 32] = zm32;
    }
    #pragma unroll
    for (int o = 32; o > 0; o >>= 1) ot += __shfl_xor(ot, o, 64);
    if (lane == 0) scores2[pair] = ot;
    asm volatile("s_waitcnt lgkmcnt(0)" ::: "memory");
    __builtin_amdgcn_sched_barrier(0);
    // coalesced writeback: 1650 floats = 825 float2
    #pragma unroll
    for (int t = 0; t < 13; ++t) {
        const int idx = t * 64 + lane;
        if (idx < 825) *(float2*)(base + idx * 2) = *(const float2*)&RT[idx * 2];
    }
}

// ---------------------------------------------------------------- InfoNCE loss
__global__ __launch_bounds__(256) void loss_kernel(
    const float* __restrict__ s2, float* __restrict__ out)
{
    const int i = threadIdx.x;
    const int g = i >> 2;
    const float pos = s2[i * 64 + g];
    float mx = -3.0e38f;
    for (int jj = 0; jj < 64; ++jj) mx = fmaxf(mx, s2[i * 64 + jj]);
    float sm = 0.f;
    for (int jj = 0; jj < 64; ++jj) sm += __expf(s2[i * 64 + jj] - mx);
    const float lse1 = __logf(sm) + mx;

    float mx2 = -3.0e38f;
    for (int k = 0; k < 256; ++k) {
        const bool allowed = ((k >> 2) != g) || (k == i);
        if (allowed) mx2 = fmaxf(mx2, s2[k * 64 + g]);
    }
    float sm2 = 0.f;
    for (int k = 0; k < 256; ++k) {
        const bool allowed = ((k >> 2) != g) || (k == i);
        if (allowed) sm2 += __expf(s2[k * 64 + g] - mx2);
    }
    const float lse2 = __logf(sm2) + mx2;

    float li = 0.5f * (lse1 - pos) + 0.5f * (lse2 - pos);
    #pragma unroll
    for (int o = 32; o > 0; o >>= 1) li += __shfl_xor(li, o, 64);
    __shared__ float wred[4];
    if ((i & 63) == 0) wred[i >> 6] = li;
    __syncthreads();
    if (i == 0) out[0] = (wred[0] + wred[1] + wred[2] + wred[3]) * (1.0f / 256.0f);
}

// ---------------------------------------------------------------- launch
extern "C" void kernel_launch(void* const* d_in, const int* in_sizes, int n_in,
                              void* d_out, int out_size, void* d_ws, size_t ws_size,
                              hipStream_t stream)
{
    const float* x      = (const float*)d_in[0];
    const float* y      = (const float*)d_in[1];
    const float* d_im   = (const float*)d_in[2];
    const float* d_lang = (const float*)d_in[3];
    const int* ymask    = (const int*)d_in[4];
    float* out = (float*)d_out;
    float* ws  = (float*)d_ws;

    float* s2          = ws;                                  // 16384 floats
    unsigned short* xb = (unsigned short*)(ws + 16384);       // 12544*512 bf16
    unsigned short* yb = xb + (size_t)XROWS * HD;             // 2048*512 bf16

    normcvt_kernel<<<(XROWS + YROWS + 3) / 4, 256, 0, stream>>>(x, y, xb, yb);
    fused_kernel<<<4096, 256, 0, stream>>>(xb, yb, ymask, d_im, d_lang, out, s2);
    loss_kernel<<<1, 256, 0, stream>>>(s2, out + (size_t)16384 * BSTRIDE);
}

// Round 11
// 294.321 us; speedup vs baseline: 1.0659x; 1.0659x over previous
//
#include <hip/hip_runtime.h>
#include <math.h>

#define XROWS 12544      // 256*49
#define YROWS 2048       // 64*32
#define HD 512
#define NM 49
#define NL 32
#define MP1 50
#define LP1 33
#define BSTRIDE 1650     // (m+1)*(L+1)
#define INVREG 10.0f

typedef __attribute__((ext_vector_type(8))) short short8;
typedef __attribute__((ext_vector_type(4))) float floatx4;

__device__ __forceinline__ unsigned short f2bf(float f) {
    unsigned int u = __builtin_bit_cast(unsigned int, f);
    u = (u + 0x7FFFu + ((u >> 16) & 1u)) >> 16;
    return (unsigned short)u;
}

__device__ __forceinline__ void gload_lds16(const void* g, void* l) {
    typedef const __attribute__((address_space(1))) unsigned int* gp_t;
    typedef __attribute__((address_space(3))) unsigned int* lp_t;
    __builtin_amdgcn_global_load_lds((gp_t)g, (lp_t)l, 16, 0, 0);
}

// ------------------------------------------------ normalize + cast to bf16
__global__ __launch_bounds__(256) void normcvt_kernel(
    const float* __restrict__ x, const float* __restrict__ y,
    unsigned short* __restrict__ xb, unsigned short* __restrict__ yb)
{
    const int wid = blockIdx.x * 4 + (threadIdx.x >> 6);
    const int lane = threadIdx.x & 63;
    if (wid >= XROWS + YROWS) return;
    const float* src;
    unsigned short* dst;
    if (wid < XROWS) { src = x + (size_t)wid * HD;           dst = xb + (size_t)wid * HD; }
    else             { src = y + (size_t)(wid - XROWS) * HD; dst = yb + (size_t)(wid - XROWS) * HD; }
    const float4 v0 = *(const float4*)(src + lane * 8);
    const float4 v1 = *(const float4*)(src + lane * 8 + 4);
    float s = v0.x*v0.x + v0.y*v0.y + v0.z*v0.z + v0.w*v0.w
            + v1.x*v1.x + v1.y*v1.y + v1.z*v1.z + v1.w*v1.w;
    #pragma unroll
    for (int o = 32; o > 0; o >>= 1) s += __shfl_xor(s, o, 64);
    const float inv = 1.0f / fmaxf(sqrtf(s), 1e-12f);
    short8 ov;
    ov[0] = (short)f2bf(v0.x * inv); ov[1] = (short)f2bf(v0.y * inv);
    ov[2] = (short)f2bf(v0.z * inv); ov[3] = (short)f2bf(v0.w * inv);
    ov[4] = (short)f2bf(v1.x * inv); ov[5] = (short)f2bf(v1.y * inv);
    ov[6] = (short)f2bf(v1.z * inv); ov[7] = (short)f2bf(v1.w * inv);
    *(short8*)(dst + lane * 8) = ov;
}

// ------------------------------------------------ bf16 MFMA GEMM (r6 version)
// C[12544 x 2048] = Xb * Yb^T, scattered into d_out at ((i*64+j)*1650 + p*32+l)
#define BM 128
#define BN 128
#define BK 32

__global__ __launch_bounds__(256) void mfma_gemm_kernel(
    const unsigned short* __restrict__ xb, const unsigned short* __restrict__ yb,
    float* __restrict__ outS)
{
    __shared__ unsigned short lA[BM * BK];   // 8 KB, row-major [128][32]
    __shared__ unsigned short lB[BN * BK];   // 8 KB, row-major [128][32]
    const int tid  = threadIdx.x;
    const int lane = tid & 63;
    const int wv   = tid >> 6;          // wave 0..3
    const int wr   = wv >> 1, wc = wv & 1;
    const int mblk = blockIdx.x >> 4;   // 0..97
    const int nblk = blockIdx.x & 15;   // fastest -> A-tile L2 reuse
    const int m0 = mblk * BM, n0 = nblk * BN;

    floatx4 acc[4][4] = {};

    const int srow = tid >> 2;          // 0..63 (staging row within pass)
    const int skq  = (tid & 3) * 8;     // k offset, 8 bf16 = 16 B

    for (int kt = 0; kt < HD / BK; ++kt) {
        const int k0 = kt * BK;
        __syncthreads();                 // previous compute done before overwrite
        gload_lds16(xb + (size_t)(m0 +      srow) * HD + k0 + skq, (char*)lA +        wv * 1024);
        gload_lds16(xb + (size_t)(m0 + 64 + srow) * HD + k0 + skq, (char*)lA + 4096 + wv * 1024);
        gload_lds16(yb + (size_t)(n0 +      srow) * HD + k0 + skq, (char*)lB +        wv * 1024);
        gload_lds16(yb + (size_t)(n0 + 64 + srow) * HD + k0 + skq, (char*)lB + 4096 + wv * 1024);
        __syncthreads();                 // compiler drains vmcnt(0) here

        const int krow = (lane >> 4) * 8;
        short8 aF[4], bF[4];
        #pragma unroll
        for (int mi = 0; mi < 4; ++mi)
            aF[mi] = *(const short8*)&lA[(wr * 64 + mi * 16 + (lane & 15)) * BK + krow];
        #pragma unroll
        for (int ni = 0; ni < 4; ++ni)
            bF[ni] = *(const short8*)&lB[(wc * 64 + ni * 16 + (lane & 15)) * BK + krow];
        #pragma unroll
        for (int mi = 0; mi < 4; ++mi)
            #pragma unroll
            for (int ni = 0; ni < 4; ++ni)
                acc[mi][ni] = __builtin_amdgcn_mfma_f32_16x16x32_bf16(
                    aF[mi], bF[ni], acc[mi][ni], 0, 0, 0);
    }

    // epilogue: C/D layout col=lane&15, row=(lane>>4)*4+q  (m89-verified)
    #pragma unroll
    for (int mi = 0; mi < 4; ++mi) {
        #pragma unroll
        for (int q = 0; q < 4; ++q) {
            const int r = m0 + wr * 64 + mi * 16 + (lane >> 4) * 4 + q;
            const int i = r / NM;
            const int p = r - i * NM;
            #pragma unroll
            for (int ni = 0; ni < 4; ++ni) {
                const int c = n0 + wc * 64 + ni * 16 + (lane & 15);
                const int j = c >> 5, lc = c & 31;
                outS[(size_t)(i * 64 + j) * BSTRIDE + p * 32 + lc] = acc[mi][ni][q];
            }
        }
    }
}

// ---------------------------------------------------------------- sinkhorn: TWO waves per pair
// wave0 owns rows (kr[33] regs), wave1 owns cols (kc[52] regs) -> each wave's
// state fits in arch VGPRs (no AGPR shuttle). Scores staged once to LDS at
// stride 33 (odd -> conflict-free rows AND cols). eu/ev exchanged via LDS,
// plain __syncthreads, no scheduling fences.
__global__ __launch_bounds__(128, 2) void sinkhorn2_kernel(
    float* __restrict__ outZ,
    const int* __restrict__ ymask,
    const float* __restrict__ d_im, const float* __restrict__ d_lang,
    float* __restrict__ scores2)
{
    const int wv   = threadIdx.x >> 6;     // 0 = row wave, 1 = col wave
    const int lane = threadIdx.x & 63;
    const int tid  = threadIdx.x;
    const int pair = blockIdx.x;
    const int j = pair & 63;
    __shared__ alignas(16) float T[1744];
    float* EV = T;          // 36 floats (pads 33..35 = 0), 16B aligned
    float* EU = T + 36;     // 52 floats (pads 50,51 = 0), 16B aligned (144B)
    float* ST = T + 88;     // 50x33 scores tile -> later Zm staging
    float* base = outZ + (size_t)pair * BSTRIDE;

    // ---- masks / dustbins (both waves compute independently) ----
    const int mval = (lane < NL) ? (ymask[j * NL + lane] != 0) : 1;
    const unsigned long long vbm = __ballot(lane < NL && !mval);  // bit c = col valid
    const float ns = (float)__popcll(vbm);
    const float kim   = __expf(fminf(fmaxf(d_im[0],   -1.f), 1.f) * INVREG);
    const float klang = __expf(fminf(fmaxf(d_lang[0], -1.f), 1.f) * INVREG);

    // ---- stage scores (49x32 block, global stride 32) into ST stride 33 ----
    for (int t = tid; t < NM * NL; t += 128) {
        const int p = t >> 5, c = t & 31;
        ST[p * 33 + c] = base[t];
    }
    // EV/EU init + pads
    const bool colA = (lane < NL) ? (((vbm >> lane) & 1ull) != 0ull) : (lane == NL);
    if (wv == 0) {
        if (lane < LP1)      EV[lane] = colA ? 1.f : 0.f;
        else if (lane < 36)  EV[lane] = 0.f;
    } else {
        if (lane >= 50 && lane < 52) EU[lane] = 0.f;
    }
    __syncthreads();

    // ---- per-wave register state ----
    float kr[33];        // wave0: row lane's K values
    float kc[52];        // wave1: col lane's K values
    if (wv == 0) {
        #pragma unroll
        for (int c = 0; c < 33; ++c) kr[c] = 0.f;
        if (lane < NM) {
            #pragma unroll
            for (int c = 0; c < NL; ++c)
                kr[c] = ((vbm >> c) & 1ull) ? __expf(ST[lane * 33 + c] * INVREG) : 0.f;
        } else if (lane == NM) {
            #pragma unroll
            for (int c = 0; c < NL; ++c) kr[c] = ((vbm >> c) & 1ull) ? klang : 0.f;
        }
        kr[32] = kim;
    } else {
        #pragma unroll
        for (int p = 0; p < 52; ++p) kc[p] = 0.f;
        if (lane < NL && colA) {
            #pragma unroll
            for (int p = 0; p < NM; ++p) kc[p] = __expf(ST[p * 33 + lane] * INVREG);
            kc[NM] = klang;
        } else if (lane == NL) {
            #pragma unroll
            for (int p = 0; p < MP1; ++p) kc[p] = kim;   // dustbin col (incl alpha corner)
        }
    }

    const float mup = (lane < NM) ? 1.f : ns;     // wave0, lane 49 -> ns
    const float nup = (lane < NL) ? 1.f : 49.f;   // wave1, lane 32 -> m
    float eu = 0.f;

    // ---- 10 iterations, alternating waves, 2 barriers each ----
    for (int it = 0; it < 10; ++it) {
        if (wv == 0) {
            float a0 = 0.f, a1 = 0.f, a2 = 0.f, a3 = 0.f;
            #pragma unroll
            for (int q = 0; q < 8; ++q) {
                const float4 e = *(const float4*)&EV[q * 4];   // broadcast
                a0 = fmaf(kr[q*4+0], e.x, a0);
                a1 = fmaf(kr[q*4+1], e.y, a1);
                a2 = fmaf(kr[q*4+2], e.z, a2);
                a3 = fmaf(kr[q*4+3], e.w, a3);
            }
            eu = __fdividef(mup, ((a0 + a1) + (a2 + a3)) + kr[32] * EV[32]);
            if (lane < MP1) EU[lane] = eu;
        }
        __syncthreads();
        if (wv == 1) {
            float b0 = 0.f, b1 = 0.f, b2 = 0.f, b3 = 0.f;
            #pragma unroll
            for (int q = 0; q < 13; ++q) {
                const float4 u4 = *(const float4*)&EU[q * 4];  // broadcast
                b0 = fmaf(kc[q*4+0], u4.x, b0);
                b1 = fmaf(kc[q*4+1], u4.y, b1);
                b2 = fmaf(kc[q*4+2], u4.z, b2);
                b3 = fmaf(kc[q*4+3], u4.w, b3);
            }
            const float Sv = (b0 + b1) + (b2 + b3);
            if (lane < LP1) EV[lane] = colA ? __fdividef(nup, Sv) : 0.f;
        }
        __syncthreads();
    }

    // ---- epilogue (wave0): Zm row -> ST; ot += 10*score*zm over 49x32 ----
    float ot = 0.f;
    if (wv == 0 && lane < MP1) {
        #pragma unroll
        for (int q = 0; q < 8; ++q) {
            const float4 e = *(const float4*)&EV[q * 4];
            #pragma unroll
            for (int t = 0; t < 4; ++t) {
                const int c = q * 4 + t;
                const float evc = (t == 0) ? e.x : (t == 1) ? e.y : (t == 2) ? e.z : e.w;
                const float zm = kr[c] * eu * evc;
                if (lane < NM) {
                    const float sc = ST[lane * 33 + c];      // raw score (read before overwrite)
                    ot = fmaf(sc * INVREG, zm, ot);          // score/TEMP * zm
                }
                ST[lane * 33 + c] = zm;
            }
        }
        ST[lane * 33 + 32] = kr[32] * eu * EV[32];
    }
    if (wv == 0) {
        #pragma unroll
        for (int o = 32; o > 0; o >>= 1) ot += __shfl_xor(ot, o, 64);
        if (lane == 0) scores2[pair] = ot;
    }
    __syncthreads();
    // coalesced writeback: 1650 floats = 825 float2 (ST is 8B aligned)
    for (int t = tid; t < 825; t += 128)
        *(float2*)(base + t * 2) = *(const float2*)&ST[t * 2];
}

// ---------------------------------------------------------------- InfoNCE loss
__global__ __launch_bounds__(256) void loss_kernel(
    const float* __restrict__ s2, float* __restrict__ out)
{
    const int i = threadIdx.x;
    const int g = i >> 2;
    const float pos = s2[i * 64 + g];
    float mx = -3.0e38f;
    for (int jj = 0; jj < 64; ++jj) mx = fmaxf(mx, s2[i * 64 + jj]);
    float sm = 0.f;
    for (int jj = 0; jj < 64; ++jj) sm += __expf(s2[i * 64 + jj] - mx);
    const float lse1 = __logf(sm) + mx;

    float mx2 = -3.0e38f;
    for (int k = 0; k < 256; ++k) {
        const bool allowed = ((k >> 2) != g) || (k == i);
        if (allowed) mx2 = fmaxf(mx2, s2[k * 64 + g]);
    }
    float sm2 = 0.f;
    for (int k = 0; k < 256; ++k) {
        const bool allowed = ((k >> 2) != g) || (k == i);
        if (allowed) sm2 += __expf(s2[k * 64 + g] - mx2);
    }
    const float lse2 = __logf(sm2) + mx2;

    float li = 0.5f * (lse1 - pos) + 0.5f * (lse2 - pos);
    #pragma unroll
    for (int o = 32; o > 0; o >>= 1) li += __shfl_xor(li, o, 64);
    __shared__ float wred[4];
    if ((i & 63) == 0) wred[i >> 6] = li;
    __syncthreads();
    if (i == 0) out[0] = (wred[0] + wred[1] + wred[2] + wred[3]) * (1.0f / 256.0f);
}

// ---------------------------------------------------------------- launch
extern "C" void kernel_launch(void* const* d_in, const int* in_sizes, int n_in,
                              void* d_out, int out_size, void* d_ws, size_t ws_size,
                              hipStream_t stream)
{
    const float* x      = (const float*)d_in[0];
    const float* y      = (const float*)d_in[1];
    const float* d_im   = (const float*)d_in[2];
    const float* d_lang = (const float*)d_in[3];
    const int* ymask    = (const int*)d_in[4];
    float* out = (float*)d_out;
    float* ws  = (float*)d_ws;

    float* s2          = ws;                                  // 16384 floats
    unsigned short* xb = (unsigned short*)(ws + 16384);       // 12544*512 bf16
    unsigned short* yb = xb + (size_t)XROWS * HD;             // 2048*512 bf16

    normcvt_kernel<<<(XROWS + YROWS + 3) / 4, 256, 0, stream>>>(x, y, xb, yb);
    mfma_gemm_kernel<<<(XROWS / BM) * (YROWS / BN), 256, 0, stream>>>(xb, yb, out);
    sinkhorn2_kernel<<<16384, 128, 0, stream>>>(out, ymask, d_im, d_lang, s2);
    loss_kernel<<<1, 256, 0, stream>>>(s2, out + (size_t)16384 * BSTRIDE);
}

// Round 12
// 196.326 us; speedup vs baseline: 1.5980x; 1.4991x over previous
//
#include <hip/hip_runtime.h>
#include <math.h>

#define XROWS 12544      // 256*49
#define YROWS 2048       // 64*32
#define HD 512
#define NM 49
#define NL 32
#define MP1 50
#define LP1 33
#define BSTRIDE 1650     // (m+1)*(L+1)
#define INVREG 10.0f
#define XPAD 520         // padded x-row stride in bf16 (1040 B; 1040/4 mod 32 = 4 -> 2-way max)

typedef __attribute__((ext_vector_type(8))) short short8;
typedef __attribute__((ext_vector_type(4))) float floatx4;

__device__ __forceinline__ unsigned short f2bf(float f) {
    unsigned int u = __builtin_bit_cast(unsigned int, f);
    u = (u + 0x7FFFu + ((u >> 16) & 1u)) >> 16;
    return (unsigned short)u;
}

__device__ __forceinline__ void gload_lds16(const void* g, void* l) {
    typedef const __attribute__((address_space(1))) unsigned int* gp_t;
    typedef __attribute__((address_space(3))) unsigned int* lp_t;
    __builtin_amdgcn_global_load_lds((gp_t)g, (lp_t)l, 16, 0, 0);
}

__device__ __forceinline__ float rl(float v, int l) {   // wave-uniform broadcast (SGPR)
    return __builtin_bit_cast(float, __builtin_amdgcn_readlane(__builtin_bit_cast(int, v), l));
}

// ------------------------------------------------ normalize + cast to bf16
__global__ __launch_bounds__(256) void normcvt_kernel(
    const float* __restrict__ x, const float* __restrict__ y,
    unsigned short* __restrict__ xb, unsigned short* __restrict__ yb)
{
    const int wid = blockIdx.x * 4 + (threadIdx.x >> 6);
    const int lane = threadIdx.x & 63;
    if (wid >= XROWS + YROWS) return;
    const float* src;
    unsigned short* dst;
    if (wid < XROWS) { src = x + (size_t)wid * HD;           dst = xb + (size_t)wid * HD; }
    else             { src = y + (size_t)(wid - XROWS) * HD; dst = yb + (size_t)(wid - XROWS) * HD; }
    const float4 v0 = *(const float4*)(src + lane * 8);
    const float4 v1 = *(const float4*)(src + lane * 8 + 4);
    float s = v0.x*v0.x + v0.y*v0.y + v0.z*v0.z + v0.w*v0.w
            + v1.x*v1.x + v1.y*v1.y + v1.z*v1.z + v1.w*v1.w;
    #pragma unroll
    for (int o = 32; o > 0; o >>= 1) s += __shfl_xor(s, o, 64);
    const float inv = 1.0f / fmaxf(sqrtf(s), 1e-12f);
    short8 ov;
    ov[0] = (short)f2bf(v0.x * inv); ov[1] = (short)f2bf(v0.y * inv);
    ov[2] = (short)f2bf(v0.z * inv); ov[3] = (short)f2bf(v0.w * inv);
    ov[4] = (short)f2bf(v1.x * inv); ov[5] = (short)f2bf(v1.y * inv);
    ov[6] = (short)f2bf(v1.z * inv); ov[7] = (short)f2bf(v1.w * inv);
    *(short8*)(dst + lane * 8) = ov;
}

// ------------------------------------------------ fused: block = image i x 8 langs
// Phase A: stage x_i (49 padded rows) to LDS once via global_load_lds.
// Phase B: per wave, 49x32 scores via MFMA (A-frags from LDS, B-frags from L2).
// Phase C: per-wave readlane sinkhorn (r7/r8-proven), private LDS scratch
//          reusing the x-stage region after a block barrier.
__global__ __launch_bounds__(512, 4) void fused_kernel(
    const unsigned short* __restrict__ xb, const unsigned short* __restrict__ yb,
    const int* __restrict__ ymask,
    const float* __restrict__ d_im, const float* __restrict__ d_lang,
    float* __restrict__ outZ, float* __restrict__ scores2)
{
    const int wv   = threadIdx.x >> 6;        // 0..7
    const int lane = threadIdx.x & 63;
    const int i  = blockIdx.x >> 3;
    const int j  = (blockIdx.x & 7) * 8 + wv;
    const int pair = i * 64 + j;
    __shared__ alignas(16) float LDSU[13472];   // 53.9 KB: x-stage, then 8x1684 scratch
    char* XSB = (char*)LDSU;
    float* zs = LDSU + wv * 1684;               // per-wave scratch (rowtile/overlay/Zm)
    float* base = outZ + (size_t)pair * BSTRIDE;

    // ---- phase A: stage x_i rows (row stride 1040 B) ----
    #pragma unroll
    for (int pass = 0; pass < 7; ++pass) {
        const int row = pass * 8 + wv;
        if (row < NM)
            gload_lds16(xb + ((size_t)i * NM + row) * HD + lane * 8, XSB + row * 1040);
    }
    __syncthreads();                            // drains vmcnt; stage visible to all

    // ---- masks / dustbins ----
    const int mval = (lane < NL) ? (ymask[j * NL + lane] != 0) : 1;
    const unsigned long long vbm = __ballot(lane < NL && !mval);  // bit c = col valid
    const float ns = (float)__popcll(vbm);
    const float kim   = __expf(fminf(fmaxf(d_im[0],   -1.f), 1.f) * INVREG);
    const float klang = __expf(fminf(fmaxf(d_lang[0], -1.f), 1.f) * INVREG);

    // ---- phase B: scores via MFMA ----
    const int la = lane & 15;
    const int koff = (lane >> 4) * 8;
    const unsigned short* yr0 = yb + ((size_t)j * NL + la) * HD + koff;
    const unsigned short* yr1 = yr0 + 16 * HD;

    floatx4 acc[4][2] = {};
    #pragma unroll
    for (int kt = 0; kt < 16; ++kt) {
        const int kb = (kt * 32 + koff) * 2;    // byte offset within padded row
        const short8 a0 = *(const short8*)(XSB + (0  + la) * 1040 + kb);
        const short8 a1 = *(const short8*)(XSB + (16 + la) * 1040 + kb);
        const short8 a2 = *(const short8*)(XSB + (32 + la) * 1040 + kb);
        const short8 a3 = *(const short8*)(XSB + 48 * 1040 + kb);   // uniform row 48 (broadcast)
        const short8 b0 = *(const short8*)(yr0 + kt * 32);
        const short8 b1 = *(const short8*)(yr1 + kt * 32);
        acc[0][0] = __builtin_amdgcn_mfma_f32_16x16x32_bf16(a0, b0, acc[0][0], 0, 0, 0);
        acc[0][1] = __builtin_amdgcn_mfma_f32_16x16x32_bf16(a0, b1, acc[0][1], 0, 0, 0);
        acc[1][0] = __builtin_amdgcn_mfma_f32_16x16x32_bf16(a1, b0, acc[1][0], 0, 0, 0);
        acc[1][1] = __builtin_amdgcn_mfma_f32_16x16x32_bf16(a1, b1, acc[1][1], 0, 0, 0);
        acc[2][0] = __builtin_amdgcn_mfma_f32_16x16x32_bf16(a2, b0, acc[2][0], 0, 0, 0);
        acc[2][1] = __builtin_amdgcn_mfma_f32_16x16x32_bf16(a2, b1, acc[2][1], 0, 0, 0);
        acc[3][0] = __builtin_amdgcn_mfma_f32_16x16x32_bf16(a3, b0, acc[3][0], 0, 0, 0);
        acc[3][1] = __builtin_amdgcn_mfma_f32_16x16x32_bf16(a3, b1, acc[3][1], 0, 0, 0);
    }
    __syncthreads();                            // all x-LDS reads done -> scratch reuse safe

    // ---- repack acc -> zs row-major stride 33 (rows 0..49; tile3 row48 valid) ----
    #pragma unroll
    for (int mi = 0; mi < 4; ++mi) {
        #pragma unroll
        for (int q = 0; q < 4; ++q) {
            const int row = mi * 16 + (lane >> 4) * 4 + q;
            if (row < MP1) {
                zs[row * 33 + la]      = acc[mi][0][q];
                zs[row * 33 + 16 + la] = acc[mi][1][q];
            }
        }
    }
    asm volatile("s_waitcnt lgkmcnt(0)" ::: "memory");
    __builtin_amdgcn_sched_barrier(0);

    // ---- kr[33] from zs (lane p = row p) ----
    float kr[33];
    #pragma unroll
    for (int c = 0; c < 33; ++c) kr[c] = 0.f;
    if (lane < NM) {
        #pragma unroll
        for (int c = 0; c < NL; ++c) {
            const float sc = zs[lane * 33 + c];
            kr[c] = ((vbm >> c) & 1ull) ? __expf(sc * INVREG) : 0.f;
        }
    } else if (lane == NM) {                    // dustbin row p=49
        #pragma unroll
        for (int c = 0; c < NL; ++c) kr[c] = ((vbm >> c) & 1ull) ? klang : 0.f;
    }
    kr[32] = kim;
    asm volatile("s_waitcnt lgkmcnt(0)" ::: "memory");
    __builtin_amdgcn_sched_barrier(0);

    // ---- one-time transpose: overlay stride 51 (51*33=1683 <= 1684) ----
    if (lane < MP1) {
        #pragma unroll
        for (int c = 0; c < 33; ++c) zs[c * 51 + lane] = kr[c];
    }
    asm volatile("s_waitcnt lgkmcnt(0)" ::: "memory");
    __builtin_amdgcn_sched_barrier(0);
    float kc[50];
    #pragma unroll
    for (int p = 0; p < 50; ++p) kc[p] = 0.f;
    if (lane < LP1) {
        #pragma unroll
        for (int p = 0; p < 50; ++p) kc[p] = zs[lane * 51 + p];
    }

    const float mup = (lane < NM) ? 1.f : ns;     // lane 49 -> ns
    const float nup = (lane < NL) ? 1.f : 49.f;   // lane 32 -> m
    const bool colA = (lane < NL) ? (((vbm >> lane) & 1ull) != 0ull) : (lane == NL);
    float eu = 0.f;
    float ev = colA ? 1.f : 0.f;

    // ---- 10 iterations, pure VALU/SALU (readlane broadcasts) ----
    for (int it = 0; it < 10; ++it) {
        float a0 = 0.f, a1 = 0.f, a2 = 0.f, a3 = 0.f;
        #pragma unroll
        for (int c = 0; c < 33; c += 4) {
            a0 = fmaf(kr[c], rl(ev, c), a0);
            if (c + 1 < 33) a1 = fmaf(kr[c+1], rl(ev, c+1), a1);
            if (c + 2 < 33) a2 = fmaf(kr[c+2], rl(ev, c+2), a2);
            if (c + 3 < 33) a3 = fmaf(kr[c+3], rl(ev, c+3), a3);
        }
        eu = __fdividef(mup, (a0 + a1) + (a2 + a3));

        a0 = a1 = a2 = a3 = 0.f;
        #pragma unroll
        for (int p = 0; p < 50; p += 4) {
            a0 = fmaf(kc[p], rl(eu, p), a0);
            if (p + 1 < 50) a1 = fmaf(kc[p+1], rl(eu, p+1), a1);
            if (p + 2 < 50) a2 = fmaf(kc[p+2], rl(eu, p+2), a2);
            if (p + 3 < 50) a3 = fmaf(kc[p+3], rl(eu, p+3), a3);
        }
        const float Sv = (a0 + a1) + (a2 + a3);
        ev = colA ? __fdividef(nup, Sv) : 0.f;
    }

    // ---- epilogue: Zm = kr*eu*ev staged to zs; ot from lnK (= score/TEMP) ----
    float ot = 0.f;
    if (lane < MP1) {
        #pragma unroll
        for (int c = 0; c < 33; ++c) {
            const float zm = kr[c] * eu * rl(ev, c);
            zs[lane * 33 + c] = zm;
            if (lane < NM && c < NL && kr[c] > 0.f)
                ot = fmaf(__logf(kr[c]), zm, ot);   // lnK = 10*score = score/TEMP
        }
    }
    #pragma unroll
    for (int o = 32; o > 0; o >>= 1) ot += __shfl_xor(ot, o, 64);
    if (lane == 0) scores2[pair] = ot;
    asm volatile("s_waitcnt lgkmcnt(0)" ::: "memory");
    __builtin_amdgcn_sched_barrier(0);
    // coalesced writeback: 1650 floats = 825 float2
    #pragma unroll
    for (int t = 0; t < 13; ++t) {
        const int idx = t * 64 + lane;
        if (idx < 825) *(float2*)(base + idx * 2) = *(const float2*)&zs[idx * 2];
    }
}

// ---------------------------------------------------------------- InfoNCE loss
__global__ __launch_bounds__(256) void loss_kernel(
    const float* __restrict__ s2, float* __restrict__ out)
{
    const int i = threadIdx.x;
    const int g = i >> 2;
    const float pos = s2[i * 64 + g];
    float mx = -3.0e38f;
    for (int jj = 0; jj < 64; ++jj) mx = fmaxf(mx, s2[i * 64 + jj]);
    float sm = 0.f;
    for (int jj = 0; jj < 64; ++jj) sm += __expf(s2[i * 64 + jj] - mx);
    const float lse1 = __logf(sm) + mx;

    float mx2 = -3.0e38f;
    for (int k = 0; k < 256; ++k) {
        const bool allowed = ((k >> 2) != g) || (k == i);
        if (allowed) mx2 = fmaxf(mx2, s2[k * 64 + g]);
    }
    float sm2 = 0.f;
    for (int k = 0; k < 256; ++k) {
        const bool allowed = ((k >> 2) != g) || (k == i);
        if (allowed) sm2 += __expf(s2[k * 64 + g] - mx2);
    }
    const float lse2 = __logf(sm2) + mx2;

    float li = 0.5f * (lse1 - pos) + 0.5f * (lse2 - pos);
    #pragma unroll
    for (int o = 32; o > 0; o >>= 1) li += __shfl_xor(li, o, 64);
    __shared__ float wred[4];
    if ((i & 63) == 0) wred[i >> 6] = li;
    __syncthreads();
    if (i == 0) out[0] = (wred[0] + wred[1] + wred[2] + wred[3]) * (1.0f / 256.0f);
}

// ---------------------------------------------------------------- launch
extern "C" void kernel_launch(void* const* d_in, const int* in_sizes, int n_in,
                              void* d_out, int out_size, void* d_ws, size_t ws_size,
                              hipStream_t stream)
{
    const float* x      = (const float*)d_in[0];
    const float* y      = (const float*)d_in[1];
    const float* d_im   = (const float*)d_in[2];
    const float* d_lang = (const float*)d_in[3];
    const int* ymask    = (const int*)d_in[4];
    float* out = (float*)d_out;
    float* ws  = (float*)d_ws;

    float* s2          = ws;                                  // 16384 floats
    unsigned short* xb = (unsigned short*)(ws + 16384);       // 12544*512 bf16
    unsigned short* yb = xb + (size_t)XROWS * HD;             // 2048*512 bf16

    normcvt_kernel<<<(XROWS + YROWS + 3) / 4, 256, 0, stream>>>(x, y, xb, yb);
    fused_kernel<<<2048, 512, 0, stream>>>(xb, yb, ymask, d_im, d_lang, out, s2);
    loss_kernel<<<1, 256, 0, stream>>>(s2, out + (size_t)16384 * BSTRIDE);
}

// Round 13
// 196.250 us; speedup vs baseline: 1.5986x; 1.0004x over previous
//
#include <hip/hip_runtime.h>
#include <math.h>

#define XROWS 12544      // 256*49
#define YROWS 2048       // 64*32
#define HD 512
#define NM 49
#define NL 32
#define MP1 50
#define LP1 33
#define BSTRIDE 1650     // (m+1)*(L+1)
#define INVREG 10.0f

typedef __attribute__((ext_vector_type(8))) short short8;
typedef __attribute__((ext_vector_type(4))) float floatx4;

__device__ __forceinline__ unsigned short f2bf(float f) {
    unsigned int u = __builtin_bit_cast(unsigned int, f);
    u = (u + 0x7FFFu + ((u >> 16) & 1u)) >> 16;
    return (unsigned short)u;
}

__device__ __forceinline__ void gload_lds16(const void* g, void* l) {
    typedef const __attribute__((address_space(1))) unsigned int* gp_t;
    typedef __attribute__((address_space(3))) unsigned int* lp_t;
    __builtin_amdgcn_global_load_lds((gp_t)g, (lp_t)l, 16, 0, 0);
}

__device__ __forceinline__ float rl(float v, int l) {   // wave-uniform broadcast (SGPR)
    return __builtin_bit_cast(float, __builtin_amdgcn_readlane(__builtin_bit_cast(int, v), l));
}

// ------------------------------------------------ normalize + cast to bf16
__global__ __launch_bounds__(256) void normcvt_kernel(
    const float* __restrict__ x, const float* __restrict__ y,
    unsigned short* __restrict__ xb, unsigned short* __restrict__ yb)
{
    const int wid = blockIdx.x * 4 + (threadIdx.x >> 6);
    const int lane = threadIdx.x & 63;
    if (wid >= XROWS + YROWS) return;
    const float* src;
    unsigned short* dst;
    if (wid < XROWS) { src = x + (size_t)wid * HD;           dst = xb + (size_t)wid * HD; }
    else             { src = y + (size_t)(wid - XROWS) * HD; dst = yb + (size_t)(wid - XROWS) * HD; }
    const float4 v0 = *(const float4*)(src + lane * 8);
    const float4 v1 = *(const float4*)(src + lane * 8 + 4);
    float s = v0.x*v0.x + v0.y*v0.y + v0.z*v0.z + v0.w*v0.w
            + v1.x*v1.x + v1.y*v1.y + v1.z*v1.z + v1.w*v1.w;
    #pragma unroll
    for (int o = 32; o > 0; o >>= 1) s += __shfl_xor(s, o, 64);
    const float inv = 1.0f / fmaxf(sqrtf(s), 1e-12f);
    short8 ov;
    ov[0] = (short)f2bf(v0.x * inv); ov[1] = (short)f2bf(v0.y * inv);
    ov[2] = (short)f2bf(v0.z * inv); ov[3] = (short)f2bf(v0.w * inv);
    ov[4] = (short)f2bf(v1.x * inv); ov[5] = (short)f2bf(v1.y * inv);
    ov[6] = (short)f2bf(v1.z * inv); ov[7] = (short)f2bf(v1.w * inv);
    *(short8*)(dst + lane * 8) = ov;
}

// ------------------------------------------------ fused: block = image i x 8 langs
// Phase A: stage x_i once to LDS (global_load_lds). Phase B: per-wave 49x32
// scores via MFMA (A from LDS, B from L2). Phase C: per-wave readlane sinkhorn.
// NOTE: no min-waves in launch_bounds -> reg cap 512, so kr[33]/kc[50] can live
// in ARCH VGPRs (capped configs forced a 56-arch + AGPR-shuttle split, ~3x VALU).
__global__ __launch_bounds__(512) void fused_kernel(
    const unsigned short* __restrict__ xb, const unsigned short* __restrict__ yb,
    const int* __restrict__ ymask,
    const float* __restrict__ d_im, const float* __restrict__ d_lang,
    float* __restrict__ outZ, float* __restrict__ scores2)
{
    const int wv   = threadIdx.x >> 6;        // 0..7
    const int lane = threadIdx.x & 63;
    const int i  = blockIdx.x >> 3;
    const int j  = (blockIdx.x & 7) * 8 + wv;
    const int pair = i * 64 + j;
    __shared__ alignas(16) float LDSU[13200];   // 51.6 KB: x-stage, then 8x1650 scratch
    char* XSB = (char*)LDSU;
    float* zs = LDSU + wv * 1650;               // per-wave scratch (rowtile/transpose/Zm)
    float* base = outZ + (size_t)pair * BSTRIDE;

    // ---- phase A: stage x_i rows (row stride 1040 B) ----
    #pragma unroll
    for (int pass = 0; pass < 7; ++pass) {
        const int row = pass * 8 + wv;
        if (row < NM)
            gload_lds16(xb + ((size_t)i * NM + row) * HD + lane * 8, XSB + row * 1040);
    }
    __syncthreads();                            // drains vmcnt; stage visible to all

    // ---- masks / dustbins ----
    const int mval = (lane < NL) ? (ymask[j * NL + lane] != 0) : 1;
    const unsigned long long vbm = __ballot(lane < NL && !mval);  // bit c = col valid
    const float ns = (float)__popcll(vbm);
    const float kim   = __expf(fminf(fmaxf(d_im[0],   -1.f), 1.f) * INVREG);
    const float klang = __expf(fminf(fmaxf(d_lang[0], -1.f), 1.f) * INVREG);

    // ---- phase B: scores via MFMA ----
    const int la = lane & 15;
    const int koff = (lane >> 4) * 8;
    const unsigned short* yr0 = yb + ((size_t)j * NL + la) * HD + koff;
    const unsigned short* yr1 = yr0 + 16 * HD;

    floatx4 acc[4][2] = {};
    #pragma unroll
    for (int kt = 0; kt < 16; ++kt) {
        const int kb = (kt * 32 + koff) * 2;    // byte offset within padded row
        const short8 a0 = *(const short8*)(XSB + (0  + la) * 1040 + kb);
        const short8 a1 = *(const short8*)(XSB + (16 + la) * 1040 + kb);
        const short8 a2 = *(const short8*)(XSB + (32 + la) * 1040 + kb);
        const short8 a3 = *(const short8*)(XSB + 48 * 1040 + kb);   // uniform row 48 (broadcast)
        const short8 b0 = *(const short8*)(yr0 + kt * 32);
        const short8 b1 = *(const short8*)(yr1 + kt * 32);
        acc[0][0] = __builtin_amdgcn_mfma_f32_16x16x32_bf16(a0, b0, acc[0][0], 0, 0, 0);
        acc[0][1] = __builtin_amdgcn_mfma_f32_16x16x32_bf16(a0, b1, acc[0][1], 0, 0, 0);
        acc[1][0] = __builtin_amdgcn_mfma_f32_16x16x32_bf16(a1, b0, acc[1][0], 0, 0, 0);
        acc[1][1] = __builtin_amdgcn_mfma_f32_16x16x32_bf16(a1, b1, acc[1][1], 0, 0, 0);
        acc[2][0] = __builtin_amdgcn_mfma_f32_16x16x32_bf16(a2, b0, acc[2][0], 0, 0, 0);
        acc[2][1] = __builtin_amdgcn_mfma_f32_16x16x32_bf16(a2, b1, acc[2][1], 0, 0, 0);
        acc[3][0] = __builtin_amdgcn_mfma_f32_16x16x32_bf16(a3, b0, acc[3][0], 0, 0, 0);
        acc[3][1] = __builtin_amdgcn_mfma_f32_16x16x32_bf16(a3, b1, acc[3][1], 0, 0, 0);
    }
    __syncthreads();                            // all x-LDS reads done -> scratch reuse safe

    // ---- repack acc -> zs row-major stride 33 (rows 0..49) ----
    #pragma unroll
    for (int mi = 0; mi < 4; ++mi) {
        #pragma unroll
        for (int q = 0; q < 4; ++q) {
            const int row = mi * 16 + (lane >> 4) * 4 + q;
            if (row < MP1) {
                zs[row * 33 + la]      = acc[mi][0][q];
                zs[row * 33 + 16 + la] = acc[mi][1][q];
            }
        }
    }
    asm volatile("s_waitcnt lgkmcnt(0)" ::: "memory");
    __builtin_amdgcn_sched_barrier(0);

    // ---- kr[33] from zs (lane p = row p) ----
    float kr[33];
    #pragma unroll
    for (int c = 0; c < 33; ++c) kr[c] = 0.f;
    if (lane < NM) {
        #pragma unroll
        for (int c = 0; c < NL; ++c) {
            const float sc = zs[lane * 33 + c];
            kr[c] = ((vbm >> c) & 1ull) ? __expf(sc * INVREG) : 0.f;
        }
    } else if (lane == NM) {                    // dustbin row p=49
        #pragma unroll
        for (int c = 0; c < NL; ++c) kr[c] = ((vbm >> c) & 1ull) ? klang : 0.f;
    }
    kr[32] = kim;
    asm volatile("s_waitcnt lgkmcnt(0)" ::: "memory");
    __builtin_amdgcn_sched_barrier(0);

    // ---- one-time transpose: stride 50, region = 33*50 = 1650 exactly ----
    if (lane < MP1) {
        #pragma unroll
        for (int c = 0; c < 33; ++c) zs[c * 50 + lane] = kr[c];
    }
    asm volatile("s_waitcnt lgkmcnt(0)" ::: "memory");
    __builtin_amdgcn_sched_barrier(0);
    float kc[50];
    #pragma unroll
    for (int p = 0; p < 50; ++p) kc[p] = 0.f;
    if (lane < LP1) {
        #pragma unroll
        for (int q = 0; q < 25; ++q) {          // b64 reads, 8B aligned (50l+2q even)
            const float2 v = *(const float2*)&zs[lane * 50 + q * 2];
            kc[q*2]   = v.x;
            kc[q*2+1] = v.y;
        }
    }

    const float mup = (lane < NM) ? 1.f : ns;     // lane 49 -> ns
    const float nup = (lane < NL) ? 1.f : 49.f;   // lane 32 -> m
    const bool colA = (lane < NL) ? (((vbm >> lane) & 1ull) != 0ull) : (lane == NL);
    float eu = 0.f;
    float ev = colA ? 1.f : 0.f;

    // ---- 10 iterations, pure VALU/SALU (readlane broadcasts) ----
    for (int it = 0; it < 10; ++it) {
        float a0 = 0.f, a1 = 0.f, a2 = 0.f, a3 = 0.f;
        #pragma unroll
        for (int c = 0; c < 33; c += 4) {
            a0 = fmaf(kr[c], rl(ev, c), a0);
            if (c + 1 < 33) a1 = fmaf(kr[c+1], rl(ev, c+1), a1);
            if (c + 2 < 33) a2 = fmaf(kr[c+2], rl(ev, c+2), a2);
            if (c + 3 < 33) a3 = fmaf(kr[c+3], rl(ev, c+3), a3);
        }
        eu = __fdividef(mup, (a0 + a1) + (a2 + a3));

        a0 = a1 = a2 = a3 = 0.f;
        #pragma unroll
        for (int p = 0; p < 50; p += 4) {
            a0 = fmaf(kc[p], rl(eu, p), a0);
            if (p + 1 < 50) a1 = fmaf(kc[p+1], rl(eu, p+1), a1);
            if (p + 2 < 50) a2 = fmaf(kc[p+2], rl(eu, p+2), a2);
            if (p + 3 < 50) a3 = fmaf(kc[p+3], rl(eu, p+3), a3);
        }
        const float Sv = (a0 + a1) + (a2 + a3);
        ev = colA ? __fdividef(nup, Sv) : 0.f;
    }

    // ---- epilogue: Zm = kr*eu*ev staged to zs; ot from lnK (= score/TEMP) ----
    float ot = 0.f;
    if (lane < MP1) {
        #pragma unroll
        for (int c = 0; c < 33; ++c) {
            const float zm = kr[c] * eu * rl(ev, c);
            zs[lane * 33 + c] = zm;
            if (lane < NM && c < NL && kr[c] > 0.f)
                ot = fmaf(__logf(kr[c]), zm, ot);   // lnK = 10*score = score/TEMP
        }
    }
    #pragma unroll
    for (int o = 32; o > 0; o >>= 1) ot += __shfl_xor(ot, o, 64);
    if (lane == 0) scores2[pair] = ot;
    asm volatile("s_waitcnt lgkmcnt(0)" ::: "memory");
    __builtin_amdgcn_sched_barrier(0);
    // coalesced writeback: 1650 floats = 825 float2
    #pragma unroll
    for (int t = 0; t < 13; ++t) {
        const int idx = t * 64 + lane;
        if (idx < 825) *(float2*)(base + idx * 2) = *(const float2*)&zs[idx * 2];
    }
}

// ---------------------------------------------------------------- InfoNCE loss
__global__ __launch_bounds__(256) void loss_kernel(
    const float* __restrict__ s2, float* __restrict__ out)
{
    const int i = threadIdx.x;
    const int g = i >> 2;
    const float pos = s2[i * 64 + g];
    float mx = -3.0e38f;
    for (int jj = 0; jj < 64; ++jj) mx = fmaxf(mx, s2[i * 64 + jj]);
    float sm = 0.f;
    for (int jj = 0; jj < 64; ++jj) sm += __expf(s2[i * 64 + jj] - mx);
    const float lse1 = __logf(sm) + mx;

    float mx2 = -3.0e38f;
    for (int k = 0; k < 256; ++k) {
        const bool allowed = ((k >> 2) != g) || (k == i);
        if (allowed) mx2 = fmaxf(mx2, s2[k * 64 + g]);
    }
    float sm2 = 0.f;
    for (int k = 0; k < 256; ++k) {
        const bool allowed = ((k >> 2) != g) || (k == i);
        if (allowed) sm2 += __expf(s2[k * 64 + g] - mx2);
    }
    const float lse2 = __logf(sm2) + mx2;

    float li = 0.5f * (lse1 - pos) + 0.5f * (lse2 - pos);
    #pragma unroll
    for (int o = 32; o > 0; o >>= 1) li += __shfl_xor(li, o, 64);
    __shared__ float wred[4];
    if ((i & 63) == 0) wred[i >> 6] = li;
    __syncthreads();
    if (i == 0) out[0] = (wred[0] + wred[1] + wred[2] + wred[3]) * (1.0f / 256.0f);
}

// ---------------------------------------------------------------- launch
extern "C" void kernel_launch(void* const* d_in, const int* in_sizes, int n_in,
                              void* d_out, int out_size, void* d_ws, size_t ws_size,
                              hipStream_t stream)
{
    const float* x      = (const float*)d_in[0];
    const float* y      = (const float*)d_in[1];
    const float* d_im   = (const float*)d_in[2];
    const float* d_lang = (const float*)d_in[3];
    const int* ymask    = (const int*)d_in[4];
    float* out = (float*)d_out;
    float* ws  = (float*)d_ws;

    float* s2          = ws;                                  // 16384 floats
    unsigned short* xb = (unsigned short*)(ws + 16384);       // 12544*512 bf16
    unsigned short* yb = xb + (size_t)XROWS * HD;             // 2048*512 bf16

    normcvt_kernel<<<(XROWS + YROWS + 3) / 4, 256, 0, stream>>>(x, y, xb, yb);
    fused_kernel<<<2048, 512, 0, stream>>>(xb, yb, ymask, d_im, d_lang, out, s2);
    loss_kernel<<<1, 256, 0, stream>>>(s2, out + (size_t)16384 * BSTRIDE);
}